// Round 12
// baseline (494.605 us; speedup 1.0000x reference)
//
#include <hip/hip_runtime.h>
#include <math.h>

#define HWD 262144   // 64*64*64
#define C_CH 128
#define B_N 2
#define VT 128       // voxels per k3 tile
#define K3_BLOCKS 256
#define K3_TILES 16  // (B_N * HWD/VT) / K3_BLOCKS = 4096/256

typedef float f4 __attribute__((ext_vector_type(4)));

__device__ __forceinline__ float sigmoidf_(float v) {
    return 1.0f / (1.0f + expf(-v));
}

// Cox-de Boor B-spline bases, k=3, GRID_SIZE=5, grid range [-1,1].
__device__ __forceinline__ void bspline8(float x, float* bs) {
    float g[12];
#pragma unroll
    for (int i = 0; i < 12; ++i) g[i] = (float)(i - 3) * 0.4f - 1.0f;
    float b[11];
#pragma unroll
    for (int t = 0; t < 11; ++t) b[t] = (x >= g[t] && x < g[t + 1]) ? 1.0f : 0.0f;
#pragma unroll
    for (int j = 1; j <= 3; ++j) {
#pragma unroll
        for (int t = 0; t + j < 11; ++t) {
            b[t] = (x - g[t]) / (g[t + j] - g[t]) * b[t]
                 + (g[t + j + 1] - x) / (g[t + j + 1] - g[t + 1]) * b[t + 1];
        }
    }
#pragma unroll
    for (int t = 0; t < 8; ++t) bs[t] = b[t];
}

// ---------------- Kernel 1: per-(b,c) mean + max over 262144 voxels ----------
// One block per (b,c). 1024 threads, 64 float4 each, fixed reduction order.
__global__ __launch_bounds__(1024) void k1_pool(const float* __restrict__ x,
                                                float* __restrict__ ws) {
    int bid = blockIdx.x;                 // b*128 + c
    const float4* xp = (const float4*)(x + (size_t)bid * HWD);
    int tid = threadIdx.x;
    float s = 0.0f, m = -INFINITY;
#pragma unroll 4
    for (int i = 0; i < 64; ++i) {
        float4 v = xp[(size_t)i * 1024 + tid];
        s += (v.x + v.y) + (v.z + v.w);
        m = fmaxf(m, fmaxf(fmaxf(v.x, v.y), fmaxf(v.z, v.w)));
    }
#pragma unroll
    for (int off = 32; off > 0; off >>= 1) {
        s += __shfl_xor(s, off, 64);
        m = fmaxf(m, __shfl_xor(m, off, 64));
    }
    __shared__ float ssum[16], smax[16];
    int wave = tid >> 6, lane = tid & 63;
    if (lane == 0) { ssum[wave] = s; smax[wave] = m; }
    __syncthreads();
    if (tid == 0) {
        float S = 0.0f, M = -INFINITY;
#pragma unroll
        for (int w = 0; w < 16; ++w) { S += ssum[w]; M = fmaxf(M, smax[w]); }
        ws[bid]       = S / (float)HWD;   // y_avg
        ws[256 + bid] = M;                // y_max
    }
}

// ---------------- Kernel 2 (fused): channel att + main pass ------------------
// 256 persistent blocks (1/CU), 1024 threads. x is REGISTER-HELD per tile
// (never staged in LDS) -> copy-like streaming: LDS only carries 16B/thread
// conv partials + the 128 satt values. 2 barriers/tile. NT stores.
__global__ __launch_bounds__(1024) void k3_fused(
    const float* __restrict__ x, const float* __restrict__ ws,
    const float* __restrict__ ck1_base, const float* __restrict__ ck1_spline,
    const float* __restrict__ ck2_base, const float* __restrict__ ck2_spline,
    const float* __restrict__ conv_w,
    const float* __restrict__ sk_base, const float* __restrict__ sk_spline,
    float* __restrict__ out) {
    __shared__ float scratch[4224];      // prologue part[512*8]; loop [128][33]
    __shared__ __align__(16) float satt[VT];
    __shared__ float catts[B_N][C_CH];
    __shared__ float w2s[B_N][C_CH];
    __shared__ float h1silu[32];
    __shared__ float h1bs[32][8];
    __shared__ float out2[512];

    int tid = threadIdx.x;
    int bid = blockIdx.x;
    int col = tid >> 5;                  // [0,32): channel group
    int j   = tid & 31;                  // [0,32): voxel-quad index

    // ---- issue tile-0 loads first (overlap with catt compute) ----
    f4 rg[4];
    {
        const float* xb = x + ((size_t)bid << 7);      // it=0: b=0, v0=bid*128
#pragma unroll
        for (int m = 0; m < 4; ++m) {
            int c = m * 32 + col;
            rg[m] = *(const f4*)(xb + (size_t)c * HWD + j * 4);
        }
    }

    // ---- catt/w2 for both b (identical arithmetic & order to old k2) ----
    if (tid < 512) {                       // t = pool*256 + b*128 + i
        int pool = tid >> 8, b = (tid >> 7) & 1, i = tid & 127;
        float v = ws[pool * 256 + b * 128 + i];
        float sv = v * sigmoidf_(v);       // silu
        float bsv[8];
        bspline8(v, bsv);
#pragma unroll
        for (int r = 0; r < 8; ++r) {
            float acc = sv * ck1_base[r * 128 + i];
#pragma unroll
            for (int g = 0; g < 8; ++g)
                acc += bsv[g] * ck1_spline[(r * 128 + i) * 8 + g];
            scratch[tid * 8 + r] = acc;
        }
    }
    __syncthreads();
    if (tid < 32) {                        // t = pool*16 + b*8 + r
        int pool = tid >> 4, b = (tid >> 3) & 1, r = tid & 7;
        int tb = pool * 256 + b * 128;
        float acc = 0.0f;
        for (int i = 0; i < 128; ++i) acc += scratch[(tb + i) * 8 + r];
        float h = fmaxf(acc, 0.0f);        // relu
        h1silu[tid] = h * sigmoidf_(h);
        bspline8(h, h1bs[tid]);
    }
    __syncthreads();
    if (tid < 512) {                       // t = pool*256 + b*128 + o
        int pool = tid >> 8, b = (tid >> 7) & 1, o = tid & 127;
        float acc = 0.0f;
#pragma unroll
        for (int r = 0; r < 8; ++r) {
            int hidx = pool * 16 + b * 8 + r;
            acc += h1silu[hidx] * ck2_base[o * 8 + r];
#pragma unroll
            for (int g = 0; g < 8; ++g)
                acc += h1bs[hidx][g] * ck2_spline[(o * 8 + r) * 8 + g];
        }
        out2[tid] = acc;
    }
    __syncthreads();
    if (tid < 256) {                       // t = b*128 + o
        int b = tid >> 7, o = tid & 127;
        float catt = sigmoidf_(out2[b * 128 + o] + out2[256 + b * 128 + o]);
        catts[b][o] = catt;
        w2s[b][o]   = catt * conv_w[o];
    }
    __syncthreads();

    // ---- main loop: 16 tiles per block, x held in registers ----
    for (int it = 0; it < K3_TILES; ++it) {
        int b  = it >> 3;
        int v0 = (((it & 7) << 8) + bid) << 7;
        float* ob = out + (size_t)b * C_CH * HWD + v0;

        // prefetch next tile into registers (in flight through compute+store)
        f4 rn[4];
        int itn = it + 1;
        if (itn < K3_TILES) {
            int bn  = itn >> 3;
            int v0n = (((itn & 7) << 8) + bid) << 7;
            const float* xbn = x + (size_t)bn * C_CH * HWD + v0n;
#pragma unroll
            for (int m = 0; m < 4; ++m) {
                int c = m * 32 + col;
                rn[m] = *(const f4*)(xbn + (size_t)c * HWD + j * 4);
            }
        }

        // per-thread conv partials: 4 voxels (j*4+k), 4 channels (32m+col)
#pragma unroll
        for (int k = 0; k < 4; ++k) {
            float p = rg[0][k] * w2s[b][col]
                    + rg[1][k] * w2s[b][32 + col]
                    + rg[2][k] * w2s[b][64 + col]
                    + rg[3][k] * w2s[b][96 + col];
            scratch[(j * 4 + k) * 33 + col] = p;
        }
        __syncthreads();
        if (tid < VT) {
            float s = 0.0f;
#pragma unroll
            for (int q = 0; q < 32; ++q) s += scratch[tid * 33 + q];
            float bs[8];
            bspline8(s, bs);
            float a = s * sigmoidf_(s) * sk_base[0];
#pragma unroll
            for (int g = 0; g < 8; ++g) a += bs[g] * sk_spline[g];
            satt[tid] = sigmoidf_(a);
        }
        __syncthreads();
        // scale register-held x and NT-store (out never re-read)
        f4 sa = *(f4*)&satt[j * 4];
#pragma unroll
        for (int m = 0; m < 4; ++m) {
            int c = m * 32 + col;
            f4 o = rg[m] * catts[b][c] * sa;
            __builtin_nontemporal_store(o, (f4*)(ob + (size_t)c * HWD + j * 4));
        }
        // rotate prefetched tile into place
        if (itn < K3_TILES) {
#pragma unroll
            for (int m = 0; m < 4; ++m) rg[m] = rn[m];
        }
    }
}

extern "C" void kernel_launch(void* const* d_in, const int* in_sizes, int n_in,
                              void* d_out, int out_size, void* d_ws, size_t ws_size,
                              hipStream_t stream) {
    const float* x          = (const float*)d_in[0];
    const float* ck1_base   = (const float*)d_in[1];
    const float* ck1_spline = (const float*)d_in[2];
    const float* ck2_base   = (const float*)d_in[3];
    const float* ck2_spline = (const float*)d_in[4];
    const float* conv_w     = (const float*)d_in[5];
    const float* sk_base    = (const float*)d_in[6];
    const float* sk_spline  = (const float*)d_in[7];
    float* out = (float*)d_out;
    float* ws  = (float*)d_ws;

    k1_pool<<<B_N * C_CH, 1024, 0, stream>>>(x, ws);
    k3_fused<<<K3_BLOCKS, 1024, 0, stream>>>(x, ws, ck1_base, ck1_spline,
                                             ck2_base, ck2_spline, conv_w,
                                             sk_base, sk_spline, out);
}